// Round 2
// baseline (1630.209 us; speedup 1.0000x reference)
//
#include <hip/hip_runtime.h>
#include <hip/hip_bf16.h>
#include <math.h>

// MoELanguageZone: embed -> sigmoid(enc) -> s2c -> router(top2 of 8) ->
// 8 experts (relu mlp) weighted combine -> sigmoid(c2s) -> sigmoid(dec) -> out logits
// N=4096 tokens, D=H=1024, M=64, E=8, HE=512, V=32000.
// bf16 MFMA (16x16x32) for all big GEMMs; fp32 for s2c/router (top-k stability).
// All MFMA operands use k-packed layout pk[kb][row][8] (k = kb*8+j).
//
// Round-2 vocab GEMM: 256^2 tile, 2-K-tiles/iteration, 8 chunks with FRAGMENT
// READ-AHEAD (reads for chunk c+1 issued before chunk c's MFMA, alternating
// register sets) so the LDS pipe overlaps the MFMA pipe; counted vmcnt(4)
// gates at chunks 3 and 7 only; nontemporal logits stores.

typedef __bf16 bf16x8 __attribute__((ext_vector_type(8)));
typedef float f32x4 __attribute__((ext_vector_type(4)));

__device__ __forceinline__ ushort f2bf(float f) {
  union { float f; unsigned u; } v; v.f = f;
  unsigned u = v.u;
  u += 0x7FFFu + ((u >> 16) & 1u);   // RNE
  return (ushort)(u >> 16);
}

__device__ __forceinline__ void async16(const void* g, void* l) {
  __builtin_amdgcn_global_load_lds((const __attribute__((address_space(1))) void*)g,
                                   (__attribute__((address_space(3))) void*)l,
                                   16, 0, 0);
}

// ---------------- pack fp32 row-major (K x N) -> bf16 pk [K/8][N][8] ----------------
__global__ void pack_w_kernel(const float* __restrict__ W, ushort* __restrict__ Wpk,
                              int K, int N) {
  long t = (long)blockIdx.x * blockDim.x + threadIdx.x;
  long total = (long)(K >> 3) * N;
  if (t >= total) return;
  long kb = t / N;
  int n = (int)(t - kb * N);
  long zoff = (long)blockIdx.y * K * N;
  const float* src = W + zoff + (kb * 8) * (long)N + n;
  union { ushort u[8]; uint4 v; } o;
#pragma unroll
  for (int j = 0; j < 8; ++j) o.u[j] = f2bf(src[(long)j * N]);
  *(uint4*)(Wpk + zoff + t * 8) = o.v;
}

// ---------------- embedding gather -> x pk [128][M][8] ----------------
__global__ void embed_pk_kernel(const int* __restrict__ ids, const float* __restrict__ emb,
                                ushort* __restrict__ xpk, int M) {
  int m = blockIdx.x * blockDim.x + threadIdx.x;  // token
  int kb = blockIdx.y;                            // 0..127
  long id = ids[m];
  const float4* s = (const float4*)(emb + id * 1024 + kb * 8);
  float4 a = s[0], b = s[1];
  union { ushort u[8]; uint4 v; } o;
  o.u[0] = f2bf(a.x); o.u[1] = f2bf(a.y); o.u[2] = f2bf(a.z); o.u[3] = f2bf(a.w);
  o.u[4] = f2bf(b.x); o.u[5] = f2bf(b.y); o.u[6] = f2bf(b.z); o.u[7] = f2bf(b.w);
  *(uint4*)(xpk + ((size_t)kb * M + m) * 8) = o.v;
}

// ---------------- generic pk-bf16 MFMA GEMM (small/medium layers) ----------------
template <int WAVES_M, int WAVES_N, int WM, int WN, int ACT, int OUT>
__launch_bounds__(WAVES_M * WAVES_N * 64)
__global__ void gemm_pk(const ushort* __restrict__ A, const ushort* __restrict__ B,
                        const float* __restrict__ bias, void* __restrict__ Cout,
                        int M, int N, int K, long sA, long sB, long sBias, long sC) {
  constexpr int BM = WAVES_M * WM * 16;
  constexpr int BN = WAVES_N * WN * 16;
  constexpr int NW = WAVES_M * WAVES_N;
  constexpr int ACH = 8 * BM / 64;
  constexpr int BCH = 8 * BN / 64;

  __shared__ ushort As[8 * BM * 8];
  __shared__ ushort Bs[8 * BN * 8];

  const int tid = threadIdx.x;
  const int lane = tid & 63;
  const int wave = tid >> 6;
  const int wm = wave % WAVES_M;
  const int wn = wave / WAVES_M;
  const int m0 = blockIdx.x * BM;
  const int n0 = blockIdx.y * BN;
  const int z = blockIdx.z;

  A += (size_t)z * sA;
  B += (size_t)z * sB;
  const float* biasp = bias + (size_t)z * sBias;

  f32x4 acc[WM][WN] = {};

  const int ktiles = K >> 6;
  const int q = lane >> 4;
  const int r16 = lane & 15;

  for (int kt = 0; kt < ktiles; ++kt) {
    const int kb0 = kt * 8;
#pragma unroll
    for (int c = wave; c < ACH; c += NW) {
      int kb = c / (BM / 64);
      int hh = c % (BM / 64);
      const ushort* g = A + (((size_t)(kb0 + kb)) * M + m0 + hh * 64 + lane) * 8;
      ushort* l = &As[(kb * BM + hh * 64) * 8];
      async16(g, l);
    }
#pragma unroll
    for (int c = wave; c < BCH; c += NW) {
      int kb = c / (BN / 64);
      int hh = c % (BN / 64);
      const ushort* g = B + (((size_t)(kb0 + kb)) * N + n0 + hh * 64 + lane) * 8;
      ushort* l = &Bs[(kb * BN + hh * 64) * 8];
      async16(g, l);
    }
    __syncthreads();
#pragma unroll
    for (int kk = 0; kk < 2; ++kk) {
      bf16x8 a[WM], b[WN];
#pragma unroll
      for (int mt = 0; mt < WM; ++mt)
        a[mt] = *(const bf16x8*)&As[((kk * 4 + q) * BM + wm * WM * 16 + mt * 16 + r16) * 8];
#pragma unroll
      for (int nt = 0; nt < WN; ++nt)
        b[nt] = *(const bf16x8*)&Bs[((kk * 4 + q) * BN + wn * WN * 16 + nt * 16 + r16) * 8];
#pragma unroll
      for (int mt = 0; mt < WM; ++mt)
#pragma unroll
        for (int nt = 0; nt < WN; ++nt)
          acc[mt][nt] = __builtin_amdgcn_mfma_f32_16x16x32_bf16(a[mt], b[nt], acc[mt][nt], 0, 0, 0);
    }
    __syncthreads();
  }

#pragma unroll
  for (int mt = 0; mt < WM; ++mt) {
#pragma unroll
    for (int nt = 0; nt < WN; ++nt) {
      int col = n0 + wn * WN * 16 + nt * 16 + r16;
      float bv = biasp[col];
#pragma unroll
      for (int r = 0; r < 4; ++r) {
        int row = m0 + wm * WM * 16 + mt * 16 + q * 4 + r;
        float v = acc[mt][nt][r] + bv;
        if (ACT == 1) v = 1.f / (1.f + expf(-v));
        else if (ACT == 2) v = fmaxf(v, 0.f);
        if (OUT == 0) {
          ((float*)Cout)[(size_t)z * sC + (size_t)row * N + col] = v;
        } else {
          ((ushort*)Cout)[(size_t)z * sC + ((size_t)(col >> 3) * M + row) * 8 + (col & 7)] = f2bf(v);
        }
      }
    }
  }
}

// ============ 256x256 read-ahead pipelined GEMM (vocab projection) ============
// A: pk [K/8][Mc][8], B: pk [K/8][Nc][8], C fp32 row-major, nontemporal stores.
// 512 thr = 8 waves (2M x 4N), per-wave 128x64 out. LDS 128KB = 2 K-tile bufs.
// Iteration = 2 K-tiles (t even in buf0, t+1 in buf1), 8 chunks. Chunk c issues
// ds_reads for chunk c+1's MFMA (alternating reg sets), then runs 16 MFMA.
// Stage order: ch0/1 A(t+1)->buf1, ch2/3 B(t+2)->buf0, ch4/5 A(t+2)->buf0,
// ch6/7 B(t+3)->buf1.  vmcnt(4)+barrier gates at ch3 and ch7 only.

#define SBAR0 __builtin_amdgcn_sched_barrier(0)
#define FULLBAR { SBAR0; __builtin_amdgcn_s_barrier(); SBAR0; }

#define CH_PLAIN(STAGE_STMT, LD_STMT, MF_STMT)  \
  {                                             \
    STAGE_STMT;                                 \
    LD_STMT;                                    \
    SBAR0;                                      \
    __builtin_amdgcn_s_setprio(1);              \
    MF_STMT;                                    \
    __builtin_amdgcn_s_setprio(0);              \
    FULLBAR;                                    \
  }

#define CH_GATE(STAGE_STMT, VMC, LD_STMT, MF_STMT)          \
  {                                                         \
    STAGE_STMT;                                             \
    asm volatile("s_waitcnt vmcnt(" #VMC ")" ::: "memory"); \
    FULLBAR;                                                \
    LD_STMT;                                                \
    SBAR0;                                                  \
    __builtin_amdgcn_s_setprio(1);                          \
    MF_STMT;                                                \
    __builtin_amdgcn_s_setprio(0);                          \
    FULLBAR;                                                \
  }

template <int Mc, int Nc, int Kc>
__global__ __launch_bounds__(512, 2)
void gemm_out_pipe(const ushort* __restrict__ A, const ushort* __restrict__ B,
                   const float* __restrict__ bias, float* __restrict__ C) {
  static_assert((Kc / 64) >= 4 && (Kc / 64) % 2 == 0, "need even ktiles >= 4");
  extern __shared__ ushort lds[];  // [2][A 16384 ush | B 16384 ush] = 128 KB
  const int tid = threadIdx.x;
  const int lane = tid & 63;
  const int wave = tid >> 6;
  const int wm = wave & 1;   // 2 waves in M
  const int wn = wave >> 1;  // 4 waves in N
  const int q = lane >> 4;
  const int r16 = lane & 15;

  // XCD-bijective swizzle (grid % 8 == 0), M-inner: 16 consecutive swz on one
  // XCD share one 524KB B-panel.
  const int cpx = gridDim.x >> 3;
  const int swz = ((int)blockIdx.x & 7) * cpx + ((int)blockIdx.x >> 3);
  constexpr int mtiles = Mc >> 8;
  const int m0 = (swz % mtiles) << 8;
  const int n0 = (swz / mtiles) << 8;

  // staging coords: wave w covers kb {w>>1, (w>>1)+4}, rows (w&1)*64 + lane
  const int s_kb = wave >> 1;
  const int s_row = ((wave & 1) << 6) + lane;

  f32x4 acc[8][4] = {};
  bf16x8 aE[2][2], aO[2][2], bA[4][2], bB[4][2];

  auto stageA = [&](int kt, int h) {  // h: 0 = rows 0-127, 1 = rows 128-255
    size_t gk = ((size_t)(kt * 8 + s_kb) * Mc + m0 + h * 128 + s_row) * 8;
    ushort* l = lds + (size_t)(kt & 1) * 32768 + (s_kb * 256 + h * 128 + s_row) * 8;
    async16(A + gk, l);
    async16(A + gk + (size_t)4 * Mc * 8, l + 4 * 256 * 8);
  };
  auto stageB = [&](int kt, int h) {
    size_t gk = ((size_t)(kt * 8 + s_kb) * Nc + n0 + h * 128 + s_row) * 8;
    ushort* l = lds + (size_t)(kt & 1) * 32768 + 16384 + (s_kb * 256 + h * 128 + s_row) * 8;
    async16(B + gk, l);
    async16(B + gk + (size_t)4 * Nc * 8, l + 4 * 256 * 8);
  };
  auto LDA = [&](int buf, int QQ, bf16x8 (&a)[2][2]) {
#pragma unroll
    for (int mi = 0; mi < 2; ++mi)
#pragma unroll
      for (int kk = 0; kk < 2; ++kk)
        a[mi][kk] = *(const bf16x8*)&lds[(size_t)buf * 32768 +
                                         ((kk * 4 + q) * 256 + wm * 128 + (QQ * 2 + mi) * 16 + r16) * 8];
  };
  auto LDB = [&](int buf, bf16x8 (&b)[4][2]) {
#pragma unroll
    for (int nf = 0; nf < 4; ++nf)
#pragma unroll
      for (int kk = 0; kk < 2; ++kk)
        b[nf][kk] = *(const bf16x8*)&lds[(size_t)buf * 32768 + 16384 +
                                         ((kk * 4 + q) * 256 + wn * 64 + nf * 16 + r16) * 8];
  };
  auto MF = [&](int QQ, bf16x8 (&a)[2][2], bf16x8 (&b)[4][2]) {
#pragma unroll
    for (int kk = 0; kk < 2; ++kk)
#pragma unroll
      for (int mi = 0; mi < 2; ++mi)
#pragma unroll
        for (int nf = 0; nf < 4; ++nf)
          acc[QQ * 2 + mi][nf] =
              __builtin_amdgcn_mfma_f32_16x16x32_bf16(a[mi][kk], b[nf][kk], acc[QQ * 2 + mi][nf], 0, 0, 0);
  };

  constexpr int ktiles = Kc >> 6;

  // ---- prologue: B(0), A(0), B(1) staged; wait all but B(1); read b(0), a(0,q0)
  stageB(0, 0); stageB(0, 1);
  stageA(0, 0); stageA(0, 1);
  stageB(1, 0); stageB(1, 1);
  asm volatile("s_waitcnt vmcnt(4)" ::: "memory");
  FULLBAR;
  LDB(0, bA);
  LDA(0, 0, aE);

  // ---- steady iterations: tiles (t, t+1), t = 0,2,..,ktiles-4
  for (int J = 0; J < ktiles / 2 - 1; ++J) {
    const int t = 2 * J;
    CH_PLAIN(stageA(t + 1, 0), LDA(0, 1, aO), MF(0, aE, bA));
    CH_PLAIN(stageA(t + 1, 1), LDA(0, 2, aE), MF(1, aO, bA));
    CH_PLAIN(stageB(t + 2, 0), LDA(0, 3, aO), MF(2, aE, bA));
    CH_GATE (stageB(t + 2, 1), 4, { LDB(1, bB); LDA(1, 0, aE); }, MF(3, aO, bA));
    CH_PLAIN(stageA(t + 2, 0), LDA(1, 1, aO), MF(0, aE, bB));
    CH_PLAIN(stageA(t + 2, 1), LDA(1, 2, aE), MF(1, aO, bB));
    CH_PLAIN(stageB(t + 3, 0), LDA(1, 3, aO), MF(2, aE, bB));
    CH_GATE (stageB(t + 3, 1), 4, { LDB(0, bA); LDA(0, 0, aE); }, MF(3, aO, bB));
  }

  // ---- final iteration: tiles (ktiles-2, ktiles-1), no new staging beyond A(last)
  {
    const int t = ktiles - 2;
    CH_PLAIN(stageA(t + 1, 0), LDA(0, 1, aO), MF(0, aE, bA));
    CH_PLAIN(stageA(t + 1, 1), LDA(0, 2, aE), MF(1, aO, bA));
    CH_PLAIN((void)0,          LDA(0, 3, aO), MF(2, aE, bA));
    CH_GATE ((void)0, 0, { LDB(1, bB); LDA(1, 0, aE); }, MF(3, aO, bA));
    CH_PLAIN((void)0, LDA(1, 1, aO), MF(0, aE, bB));
    CH_PLAIN((void)0, LDA(1, 2, aE), MF(1, aO, bB));
    CH_PLAIN((void)0, LDA(1, 3, aO), MF(2, aE, bB));
    __builtin_amdgcn_s_setprio(1);
    MF(3, aO, bB);
    __builtin_amdgcn_s_setprio(0);
  }

  // ---- epilogue: bias + nontemporal fp32 store (don't thrash L2/L3)
#pragma unroll
  for (int nf = 0; nf < 4; ++nf) {
    const int col = n0 + wn * 64 + nf * 16 + r16;
    const float bv = bias[col];
#pragma unroll
    for (int mf = 0; mf < 8; ++mf) {
      const int row = m0 + wm * 128 + mf * 16 + q * 4;
      float* out = C + (size_t)row * Nc + col;
#pragma unroll
      for (int r = 0; r < 4; ++r)
        __builtin_nontemporal_store(acc[mf][nf][r] + bv, out + (size_t)r * Nc);
    }
  }
}

// ---------------- fp32 s2c: cont = spikes(Mx1024) @ W(1024x64) + b ----------------
__global__ void s2c_kernel(const float* __restrict__ spikes, const float* __restrict__ W,
                           const float* __restrict__ b, float* __restrict__ cont,
                           ushort* __restrict__ contpk, int M) {
  int tid = threadIdx.x;
  int m = tid & 63;
  int n = blockIdx.x * 4 + (tid >> 6);
  const float* srow = spikes + (size_t)n * 1024;
  float acc = b[m];
#pragma unroll 8
  for (int k = 0; k < 1024; ++k) acc = fmaf(srow[k], W[k * 64 + m], acc);
  cont[(size_t)n * 64 + m] = acc;
  contpk[((size_t)(m >> 3) * M + n) * 8 + (m & 7)] = f2bf(acc);
}

// ---------------- router: tanh MLP -> softmax(8) -> top2 renorm ----------------
__global__ void router_kernel(const float* __restrict__ cont, const float* __restrict__ rW1,
                              const float* __restrict__ rb1, const float* __restrict__ rW2,
                              const float* __restrict__ rb2, float* __restrict__ probs,
                              float* __restrict__ wfull) {
  int n = blockIdx.x;
  int L = threadIdx.x;  // 64
  float c = cont[(size_t)n * 64 + L];
  float gh = rb1[L];
#pragma unroll 8
  for (int k = 0; k < 64; ++k) {
    float ck = __shfl(c, k, 64);
    gh = fmaf(ck, rW1[k * 64 + L], gh);
  }
  gh = tanhf(gh);
  __shared__ float ghs[64];
  ghs[L] = gh;
  __syncthreads();
  float lg = 0.f;
  if (L < 8) {
    lg = rb2[L];
#pragma unroll 8
    for (int h = 0; h < 64; ++h) lg = fmaf(ghs[h], rW2[h * 8 + L], lg);
  }
  float mx = lg;
  for (int o = 4; o >= 1; o >>= 1) mx = fmaxf(mx, __shfl_xor(mx, o, 8));
  float ex = expf(lg - mx);
  float sm = ex;
  for (int o = 4; o >= 1; o >>= 1) sm += __shfl_xor(sm, o, 8);
  float pr = ex / sm;
  __shared__ float ps[8];
  if (L < 8) { probs[(size_t)n * 8 + L] = pr; ps[L] = pr; }
  __syncthreads();
  if (L == 0) {
    int i1 = 0; float v1 = ps[0];
#pragma unroll
    for (int e = 1; e < 8; ++e) if (ps[e] > v1) { v1 = ps[e]; i1 = e; }
    float v2 = -1.f; int i2 = 0;
#pragma unroll
    for (int e = 0; e < 8; ++e) if (e != i1 && ps[e] > v2) { v2 = ps[e]; i2 = e; }
    float s = v1 + v2;
    float w[8];
#pragma unroll
    for (int e = 0; e < 8; ++e) w[e] = 0.f;
    w[i1] = v1 / s; w[i2] = v2 / s;
#pragma unroll
    for (int e = 0; e < 8; ++e) wfull[(size_t)n * 8 + e] = w[e];
  }
}

// ---------------- weighted expert combine -> pk bf16 (K=64 for c2s) ----------------
__global__ void combine_kernel(const float* __restrict__ eo, const float* __restrict__ wfull,
                               ushort* __restrict__ exopk, int M) {
  int t = blockIdx.x * 256 + threadIdx.x;
  int n = t >> 6, m = t & 63;
  float acc = 0.f;
#pragma unroll
  for (int e = 0; e < 8; ++e)
    acc = fmaf(wfull[(size_t)n * 8 + e], eo[((size_t)e * M + n) * 64 + m], acc);
  exopk[((size_t)(m >> 3) * M + n) * 8 + (m & 7)] = f2bf(acc);
}

extern "C" void kernel_launch(void* const* d_in, const int* in_sizes, int n_in,
                              void* d_out, int out_size, void* d_ws, size_t ws_size,
                              hipStream_t stream) {
  const int*   ids   = (const int*)  d_in[0];
  const float* emb   = (const float*)d_in[1];
  const float* enc_W = (const float*)d_in[2];
  const float* enc_b = (const float*)d_in[3];
  const float* s2c_W = (const float*)d_in[4];
  const float* s2c_b = (const float*)d_in[5];
  const float* rW1   = (const float*)d_in[6];
  const float* rb1   = (const float*)d_in[7];
  const float* rW2   = (const float*)d_in[8];
  const float* rb2   = (const float*)d_in[9];
  const float* eW1   = (const float*)d_in[10];
  const float* eb1   = (const float*)d_in[11];
  const float* eW2   = (const float*)d_in[12];
  const float* eb2   = (const float*)d_in[13];
  const float* c2s_W = (const float*)d_in[14];
  const float* c2s_b = (const float*)d_in[15];
  const float* dec_W = (const float*)d_in[16];
  const float* dec_b = (const float*)d_in[17];
  const float* out_W = (const float*)d_in[18];
  const float* out_b = (const float*)d_in[19];
  (void)in_sizes; (void)n_in; (void)out_size; (void)ws_size;

  const int M = 4096, D = 1024, H = 1024, Mm = 64, E = 8, V = 32000, HE = 512;

  char* p = (char*)d_ws;
  auto alloc = [&](size_t bytes) { void* r = (void*)p; p += (bytes + 255) & ~(size_t)255; return r; };
  ushort* xpk    = (ushort*)alloc((size_t)M * D * 2);
  ushort* encWpk = (ushort*)alloc((size_t)D * H * 2);
  float*  spikes = (float*) alloc((size_t)M * H * 4);
  float*  cont   = (float*) alloc((size_t)M * Mm * 4);
  ushort* contpk = (ushort*)alloc((size_t)M * Mm * 2);
  float*  wfull  = (float*) alloc((size_t)M * E * 4);
  ushort* eW1pk  = (ushort*)alloc((size_t)E * Mm * HE * 2);
  ushort* eW2pk  = (ushort*)alloc((size_t)E * HE * Mm * 2);
  ushort* h1pk   = (ushort*)alloc((size_t)E * M * HE * 2);
  float*  eo     = (float*) alloc((size_t)E * M * Mm * 4);
  ushort* exopk  = (ushort*)alloc((size_t)M * Mm * 2);
  ushort* c2sWpk = (ushort*)alloc((size_t)Mm * H * 2);
  ushort* smoepk = (ushort*)alloc((size_t)M * H * 2);
  ushort* decWpk = (ushort*)alloc((size_t)H * D * 2);
  ushort* decpk  = (ushort*)alloc((size_t)M * D * 2);
  ushort* outWpk = (ushort*)alloc((size_t)D * V * 2);

  float* logits = (float*)d_out;
  float* probs  = logits + (size_t)M * V;

  // one-time: allow 128KB dynamic LDS for the pipelined vocab GEMM
  static bool attr_done = false;
  if (!attr_done) {
    (void)hipFuncSetAttribute(reinterpret_cast<const void*>(&gemm_out_pipe<4096, 32000, 1024>),
                              hipFuncAttributeMaxDynamicSharedMemorySize, 131072);
    attr_done = true;
  }

  // weight packs (fp32 -> bf16 k-packed)
  pack_w_kernel<<<dim3(((D / 8) * H + 255) / 256, 1), 256, 0, stream>>>(enc_W, encWpk, D, H);
  pack_w_kernel<<<dim3(((Mm / 8) * HE + 255) / 256, E), 256, 0, stream>>>(eW1, eW1pk, Mm, HE);
  pack_w_kernel<<<dim3(((HE / 8) * Mm + 255) / 256, E), 256, 0, stream>>>(eW2, eW2pk, HE, Mm);
  pack_w_kernel<<<dim3(((Mm / 8) * H + 255) / 256, 1), 256, 0, stream>>>(c2s_W, c2sWpk, Mm, H);
  pack_w_kernel<<<dim3(((H / 8) * D + 255) / 256, 1), 256, 0, stream>>>(dec_W, decWpk, H, D);
  pack_w_kernel<<<dim3(((D / 8) * V + 255) / 256, 1), 256, 0, stream>>>(out_W, outWpk, D, V);

  // 1) embed gather -> pk
  embed_pk_kernel<<<dim3(M / 256, D / 8), 256, 0, stream>>>(ids, emb, xpk, M);
  // 2) enc: sigmoid(x @ enc_W + b) -> fp32 (router path needs precision)
  gemm_pk<2, 2, 4, 4, 1, 0><<<dim3(M / 128, H / 128, 1), 256, 0, stream>>>(
      xpk, encWpk, enc_b, spikes, M, H, D, 0, 0, 0, 0);
  // 3) s2c fp32
  s2c_kernel<<<dim3(M / 4), 256, 0, stream>>>(spikes, s2c_W, s2c_b, cont, contpk, M);
  // 4) router fp32
  router_kernel<<<dim3(M), 64, 0, stream>>>(cont, rW1, rb1, rW2, rb2, probs, wfull);
  // 5) experts: h1 = relu(cont @ eW1 + eb1)  [batched over E]
  gemm_pk<2, 2, 4, 4, 2, 1><<<dim3(M / 128, HE / 128, E), 256, 0, stream>>>(
      contpk, eW1pk, eb1, h1pk, M, HE, Mm, 0, (long)Mm * HE, HE, (long)M * HE);
  //    eo = h1 @ eW2 + eb2   (N=64 tile variant)
  gemm_pk<4, 1, 2, 4, 0, 0><<<dim3(M / 128, 1, E), 256, 0, stream>>>(
      h1pk, eW2pk, eb2, eo, M, Mm, HE, (long)M * HE, (long)HE * Mm, Mm, (long)M * Mm);
  // 6) weighted combine (top-2 weights, zeros elsewhere)
  combine_kernel<<<dim3(M * Mm / 256), 256, 0, stream>>>(eo, wfull, exopk, M);
  // 7) c2s: sigmoid(expert_out @ c2s_W + b) -> pk
  gemm_pk<2, 2, 4, 4, 1, 1><<<dim3(M / 128, H / 128, 1), 256, 0, stream>>>(
      exopk, c2sWpk, c2s_b, smoepk, M, H, Mm, 0, 0, 0, 0);
  // 8) dec: sigmoid(spikes @ dec_W + b) -> pk
  gemm_pk<2, 2, 4, 4, 1, 1><<<dim3(M / 128, D / 128, 1), 256, 0, stream>>>(
      smoepk, decWpk, dec_b, decpk, M, D, H, 0, 0, 0, 0);
  // 9) out: logits = decoded @ out_W + b  (268 GFLOP) — read-ahead pipelined kernel
  gemm_out_pipe<4096, 32000, 1024><<<dim3((M / 256) * (V / 256)), 512, 131072, stream>>>(
      decpk, outWpk, out_b, logits);
}

// Round 3
// 1129.307 us; speedup vs baseline: 1.4435x; 1.4435x over previous
//
#include <hip/hip_runtime.h>
#include <hip/hip_bf16.h>
#include <math.h>

// MoELanguageZone: embed -> sigmoid(enc) -> s2c -> router(top2 of 8) ->
// 8 experts (relu mlp) weighted combine -> sigmoid(c2s) -> sigmoid(dec) -> out logits
// N=4096 tokens, D=H=1024, M=64, E=8, HE=512, V=32000.
// bf16 MFMA (16x16x32) for all big GEMMs; fp32 for s2c/router (top-k stability).
// All MFMA operands use k-packed layout pk[kb][row][8] (k = kb*8+j).
//
// Round-3 vocab GEMM: 256^2 tile, 4 phases/K-tile with A-fragment read-ahead
// (aE/aO alternating, +16 VGPR only — round-2's bB double-set spilled at the
// 256-reg/wave budget: VGPR 128 + acc 128 AGPR = cap, +1.3GB scratch traffic).
// Single b-set; the 12-read B+aE batch for tile t+1 issues at tile t's gate
// AFTER MF(3) (sched_barrier-fenced so the compiler can't hoist-and-rename).
// Only 2 s_barriers per K-tile (end-ph1 + gate) — un-barriered phases give
// cross-wave MFMA/LDS overlap.

typedef __bf16 bf16x8 __attribute__((ext_vector_type(8)));
typedef float f32x4 __attribute__((ext_vector_type(4)));

__device__ __forceinline__ ushort f2bf(float f) {
  union { float f; unsigned u; } v; v.f = f;
  unsigned u = v.u;
  u += 0x7FFFu + ((u >> 16) & 1u);   // RNE
  return (ushort)(u >> 16);
}

__device__ __forceinline__ void async16(const void* g, void* l) {
  __builtin_amdgcn_global_load_lds((const __attribute__((address_space(1))) void*)g,
                                   (__attribute__((address_space(3))) void*)l,
                                   16, 0, 0);
}

// ---------------- pack fp32 row-major (K x N) -> bf16 pk [K/8][N][8] ----------------
__global__ void pack_w_kernel(const float* __restrict__ W, ushort* __restrict__ Wpk,
                              int K, int N) {
  long t = (long)blockIdx.x * blockDim.x + threadIdx.x;
  long total = (long)(K >> 3) * N;
  if (t >= total) return;
  long kb = t / N;
  int n = (int)(t - kb * N);
  long zoff = (long)blockIdx.y * K * N;
  const float* src = W + zoff + (kb * 8) * (long)N + n;
  union { ushort u[8]; uint4 v; } o;
#pragma unroll
  for (int j = 0; j < 8; ++j) o.u[j] = f2bf(src[(long)j * N]);
  *(uint4*)(Wpk + zoff + t * 8) = o.v;
}

// ---------------- embedding gather -> x pk [128][M][8] ----------------
__global__ void embed_pk_kernel(const int* __restrict__ ids, const float* __restrict__ emb,
                                ushort* __restrict__ xpk, int M) {
  int m = blockIdx.x * blockDim.x + threadIdx.x;  // token
  int kb = blockIdx.y;                            // 0..127
  long id = ids[m];
  const float4* s = (const float4*)(emb + id * 1024 + kb * 8);
  float4 a = s[0], b = s[1];
  union { ushort u[8]; uint4 v; } o;
  o.u[0] = f2bf(a.x); o.u[1] = f2bf(a.y); o.u[2] = f2bf(a.z); o.u[3] = f2bf(a.w);
  o.u[4] = f2bf(b.x); o.u[5] = f2bf(b.y); o.u[6] = f2bf(b.z); o.u[7] = f2bf(b.w);
  *(uint4*)(xpk + ((size_t)kb * M + m) * 8) = o.v;
}

// ---------------- generic pk-bf16 MFMA GEMM (small/medium layers) ----------------
template <int WAVES_M, int WAVES_N, int WM, int WN, int ACT, int OUT>
__launch_bounds__(WAVES_M * WAVES_N * 64)
__global__ void gemm_pk(const ushort* __restrict__ A, const ushort* __restrict__ B,
                        const float* __restrict__ bias, void* __restrict__ Cout,
                        int M, int N, int K, long sA, long sB, long sBias, long sC) {
  constexpr int BM = WAVES_M * WM * 16;
  constexpr int BN = WAVES_N * WN * 16;
  constexpr int NW = WAVES_M * WAVES_N;
  constexpr int ACH = 8 * BM / 64;
  constexpr int BCH = 8 * BN / 64;

  __shared__ ushort As[8 * BM * 8];
  __shared__ ushort Bs[8 * BN * 8];

  const int tid = threadIdx.x;
  const int lane = tid & 63;
  const int wave = tid >> 6;
  const int wm = wave % WAVES_M;
  const int wn = wave / WAVES_M;
  const int m0 = blockIdx.x * BM;
  const int n0 = blockIdx.y * BN;
  const int z = blockIdx.z;

  A += (size_t)z * sA;
  B += (size_t)z * sB;
  const float* biasp = bias + (size_t)z * sBias;

  f32x4 acc[WM][WN] = {};

  const int ktiles = K >> 6;
  const int q = lane >> 4;
  const int r16 = lane & 15;

  for (int kt = 0; kt < ktiles; ++kt) {
    const int kb0 = kt * 8;
#pragma unroll
    for (int c = wave; c < ACH; c += NW) {
      int kb = c / (BM / 64);
      int hh = c % (BM / 64);
      const ushort* g = A + (((size_t)(kb0 + kb)) * M + m0 + hh * 64 + lane) * 8;
      ushort* l = &As[(kb * BM + hh * 64) * 8];
      async16(g, l);
    }
#pragma unroll
    for (int c = wave; c < BCH; c += NW) {
      int kb = c / (BN / 64);
      int hh = c % (BN / 64);
      const ushort* g = B + (((size_t)(kb0 + kb)) * N + n0 + hh * 64 + lane) * 8;
      ushort* l = &Bs[(kb * BN + hh * 64) * 8];
      async16(g, l);
    }
    __syncthreads();
#pragma unroll
    for (int kk = 0; kk < 2; ++kk) {
      bf16x8 a[WM], b[WN];
#pragma unroll
      for (int mt = 0; mt < WM; ++mt)
        a[mt] = *(const bf16x8*)&As[((kk * 4 + q) * BM + wm * WM * 16 + mt * 16 + r16) * 8];
#pragma unroll
      for (int nt = 0; nt < WN; ++nt)
        b[nt] = *(const bf16x8*)&Bs[((kk * 4 + q) * BN + wn * WN * 16 + nt * 16 + r16) * 8];
#pragma unroll
      for (int mt = 0; mt < WM; ++mt)
#pragma unroll
        for (int nt = 0; nt < WN; ++nt)
          acc[mt][nt] = __builtin_amdgcn_mfma_f32_16x16x32_bf16(a[mt], b[nt], acc[mt][nt], 0, 0, 0);
    }
    __syncthreads();
  }

#pragma unroll
  for (int mt = 0; mt < WM; ++mt) {
#pragma unroll
    for (int nt = 0; nt < WN; ++nt) {
      int col = n0 + wn * WN * 16 + nt * 16 + r16;
      float bv = biasp[col];
#pragma unroll
      for (int r = 0; r < 4; ++r) {
        int row = m0 + wm * WM * 16 + mt * 16 + q * 4 + r;
        float v = acc[mt][nt][r] + bv;
        if (ACT == 1) v = 1.f / (1.f + expf(-v));
        else if (ACT == 2) v = fmaxf(v, 0.f);
        if (OUT == 0) {
          ((float*)Cout)[(size_t)z * sC + (size_t)row * N + col] = v;
        } else {
          ((ushort*)Cout)[(size_t)z * sC + ((size_t)(col >> 3) * M + row) * 8 + (col & 7)] = f2bf(v);
        }
      }
    }
  }
}

// ============ 256x256 A-read-ahead pipelined GEMM (vocab projection) ============
// A: pk [K/8][Mc][8], B: pk [K/8][Nc][8], C fp32 row-major. 512 thr = 8 waves
// (2M x 4N), per-wave 128x64 out. LDS 128KB = 2 K-tile bufs (A 32KB | B 32KB).
// Per K-tile t (buf = t&1, obuf = buf^1), phases 0-3:
//  ph0: issue LDA(buf,1,aO); stage A(t+1,h0)->obuf; MFMA(0,aE,b)
//  ph1: issue LDA(buf,2,aE); stage A(t+1,h1)->obuf; MFMA(1,aO,b); BARRIER
//  ph2: issue LDA(buf,3,aO); stage B(t+2,h0)->buf;  MFMA(2,aE,b)
//  ph3: stage B(t+2,h1)->buf; MFMA(3,aO,b); vmcnt(4); BARRIER;
//       issue LDB(obuf)+LDA(obuf,0,aE)  [12 reads for tile t+1]
// Registers: acc 128 (AGPR) + b 32 + aE/aO 32 VGPR — fits the 256/wave budget.

#define SBAR0 __builtin_amdgcn_sched_barrier(0)
#define BARRIER { SBAR0; __builtin_amdgcn_s_barrier(); SBAR0; }
#define PRIO1 __builtin_amdgcn_s_setprio(1)
#define PRIO0 __builtin_amdgcn_s_setprio(0)

template <int Mc, int Nc, int Kc>
__global__ __launch_bounds__(512, 2)
void gemm_out_pipe(const ushort* __restrict__ A, const ushort* __restrict__ B,
                   const float* __restrict__ bias, float* __restrict__ C) {
  static_assert((Kc / 64) >= 4 && (Kc / 64) % 2 == 0, "need even ktiles >= 4");
  extern __shared__ ushort lds[];  // [2][A 16384 ush | B 16384 ush] = 128 KB
  const int tid = threadIdx.x;
  const int lane = tid & 63;
  const int wave = tid >> 6;
  const int wm = wave & 1;   // 2 waves in M
  const int wn = wave >> 1;  // 4 waves in N
  const int q = lane >> 4;
  const int r16 = lane & 15;

  // XCD-bijective swizzle (grid % 8 == 0), M-inner: 16 consecutive swz on one
  // XCD share one 524KB B-panel.
  const int cpx = gridDim.x >> 3;
  const int swz = ((int)blockIdx.x & 7) * cpx + ((int)blockIdx.x >> 3);
  constexpr int mtiles = Mc >> 8;
  const int m0 = (swz % mtiles) << 8;
  const int n0 = (swz / mtiles) << 8;

  // staging coords: wave w covers kb {w>>1, (w>>1)+4}, rows (w&1)*64 + lane
  const int s_kb = wave >> 1;
  const int s_row = ((wave & 1) << 6) + lane;

  f32x4 acc[8][4] = {};
  bf16x8 aE[2][2], aO[2][2], b[4][2];

  auto stageA = [&](int kt, int h, int buf) {  // h: 0 = rows 0-127, 1 = rows 128-255
    const ushort* g = A + (size_t)(((kt * 8 + s_kb) * Mc + m0 + h * 128 + s_row) * 8);
    ushort* l = lds + buf * 32768 + (s_kb * 256 + h * 128 + s_row) * 8;
    async16(g, l);
    async16(g + 4 * Mc * 8, l + 4 * 256 * 8);
  };
  auto stageB = [&](int kt, int h, int buf) {
    const ushort* g = B + (size_t)(((kt * 8 + s_kb) * Nc + n0 + h * 128 + s_row) * 8);
    ushort* l = lds + buf * 32768 + 16384 + (s_kb * 256 + h * 128 + s_row) * 8;
    async16(g, l);
    async16(g + 4 * Nc * 8, l + 4 * 256 * 8);
  };
  auto LDA = [&](int buf, int QQ, bf16x8 (&a)[2][2]) {
#pragma unroll
    for (int mi = 0; mi < 2; ++mi)
#pragma unroll
      for (int kk = 0; kk < 2; ++kk)
        a[mi][kk] = *(const bf16x8*)&lds[buf * 32768 +
                                         ((kk * 4 + q) * 256 + wm * 128 + (QQ * 2 + mi) * 16 + r16) * 8];
  };
  auto LDB = [&](int buf) {
#pragma unroll
    for (int nf = 0; nf < 4; ++nf)
#pragma unroll
      for (int kk = 0; kk < 2; ++kk)
        b[nf][kk] = *(const bf16x8*)&lds[buf * 32768 + 16384 +
                                         ((kk * 4 + q) * 256 + wn * 64 + nf * 16 + r16) * 8];
  };
  auto MF = [&](int QQ, bf16x8 (&a)[2][2]) {
#pragma unroll
    for (int kk = 0; kk < 2; ++kk)
#pragma unroll
      for (int mi = 0; mi < 2; ++mi)
#pragma unroll
        for (int nf = 0; nf < 4; ++nf)
          acc[QQ * 2 + mi][nf] =
              __builtin_amdgcn_mfma_f32_16x16x32_bf16(a[mi][kk], b[nf][kk], acc[QQ * 2 + mi][nf], 0, 0, 0);
  };

  constexpr int ktiles = Kc >> 6;

  // ---- prologue: stage B(0), A(0), B(1); drain all but B(1); load b(0), aE(0)
  stageB(0, 0, 0); stageB(0, 1, 0);
  stageA(0, 0, 0); stageA(0, 1, 0);
  stageB(1, 0, 1); stageB(1, 1, 1);
  asm volatile("s_waitcnt vmcnt(4)" ::: "memory");
  BARRIER;
  LDB(0); LDA(0, 0, aE);
  SBAR0;

#define TILE_FULL(T, BUF, OBUF)                               \
  {                                                           \
    LDA(BUF, 1, aO); stageA((T) + 1, 0, OBUF);                \
    SBAR0; PRIO1; MF(0, aE); PRIO0; SBAR0;                    \
    LDA(BUF, 2, aE); stageA((T) + 1, 1, OBUF);                \
    SBAR0; PRIO1; MF(1, aO); PRIO0;                           \
    BARRIER;                                                  \
    LDA(BUF, 3, aO); stageB((T) + 2, 0, BUF);                 \
    SBAR0; PRIO1; MF(2, aE); PRIO0; SBAR0;                    \
    stageB((T) + 2, 1, BUF);                                  \
    SBAR0; PRIO1; MF(3, aO); PRIO0; SBAR0;                    \
    asm volatile("s_waitcnt vmcnt(4)" ::: "memory");          \
    BARRIER;                                                  \
    LDB(OBUF); LDA(OBUF, 0, aE);                              \
    SBAR0;                                                    \
  }

  // ---- steady: tiles 0 .. ktiles-3 (pairs; odd tile stages B(t+3) needs t<=ktiles-4)
  for (int t = 0; t < ktiles - 2; t += 2) {
    TILE_FULL(t, 0, 1);
    TILE_FULL(t + 1, 1, 0);
  }

  // ---- tile ktiles-2 (buf 0): stage only A(last); drain all; load tile-last frags
  {
    LDA(0, 1, aO); stageA(ktiles - 1, 0, 1);
    SBAR0; PRIO1; MF(0, aE); PRIO0; SBAR0;
    LDA(0, 2, aE); stageA(ktiles - 1, 1, 1);
    SBAR0; PRIO1; MF(1, aO); PRIO0;
    BARRIER;
    LDA(0, 3, aO);
    SBAR0; PRIO1; MF(2, aE); PRIO0; SBAR0;
    PRIO1; MF(3, aO); PRIO0; SBAR0;
    asm volatile("s_waitcnt vmcnt(0)" ::: "memory");
    BARRIER;
    LDB(1); LDA(1, 0, aE);
    SBAR0;
  }
  // ---- tile ktiles-1 (buf 1): bare compute
  {
    LDA(1, 1, aO);
    SBAR0; PRIO1; MF(0, aE); PRIO0; SBAR0;
    LDA(1, 2, aE);
    SBAR0; PRIO1; MF(1, aO); PRIO0; SBAR0;
    LDA(1, 3, aO);
    SBAR0; PRIO1; MF(2, aE); PRIO0; SBAR0;
    PRIO1; MF(3, aO); PRIO0;
  }
#undef TILE_FULL

  // ---- epilogue: bias + fp32 store
#pragma unroll
  for (int nf = 0; nf < 4; ++nf) {
    const int col = n0 + wn * 64 + nf * 16 + r16;
    const float bv = bias[col];
#pragma unroll
    for (int mf = 0; mf < 8; ++mf) {
      const int row = m0 + wm * 128 + mf * 16 + q * 4;
      float* out = C + (size_t)row * Nc + col;
#pragma unroll
      for (int r = 0; r < 4; ++r)
        out[(size_t)r * Nc] = acc[mf][nf][r] + bv;
    }
  }
}

// ---------------- fp32 s2c: cont = spikes(Mx1024) @ W(1024x64) + b ----------------
__global__ void s2c_kernel(const float* __restrict__ spikes, const float* __restrict__ W,
                           const float* __restrict__ b, float* __restrict__ cont,
                           ushort* __restrict__ contpk, int M) {
  int tid = threadIdx.x;
  int m = tid & 63;
  int n = blockIdx.x * 4 + (tid >> 6);
  const float* srow = spikes + (size_t)n * 1024;
  float acc = b[m];
#pragma unroll 8
  for (int k = 0; k < 1024; ++k) acc = fmaf(srow[k], W[k * 64 + m], acc);
  cont[(size_t)n * 64 + m] = acc;
  contpk[((size_t)(m >> 3) * M + n) * 8 + (m & 7)] = f2bf(acc);
}

// ---------------- router: tanh MLP -> softmax(8) -> top2 renorm ----------------
__global__ void router_kernel(const float* __restrict__ cont, const float* __restrict__ rW1,
                              const float* __restrict__ rb1, const float* __restrict__ rW2,
                              const float* __restrict__ rb2, float* __restrict__ probs,
                              float* __restrict__ wfull) {
  int n = blockIdx.x;
  int L = threadIdx.x;  // 64
  float c = cont[(size_t)n * 64 + L];
  float gh = rb1[L];
#pragma unroll 8
  for (int k = 0; k < 64; ++k) {
    float ck = __shfl(c, k, 64);
    gh = fmaf(ck, rW1[k * 64 + L], gh);
  }
  gh = tanhf(gh);
  __shared__ float ghs[64];
  ghs[L] = gh;
  __syncthreads();
  float lg = 0.f;
  if (L < 8) {
    lg = rb2[L];
#pragma unroll 8
    for (int h = 0; h < 64; ++h) lg = fmaf(ghs[h], rW2[h * 8 + L], lg);
  }
  float mx = lg;
  for (int o = 4; o >= 1; o >>= 1) mx = fmaxf(mx, __shfl_xor(mx, o, 8));
  float ex = expf(lg - mx);
  float sm = ex;
  for (int o = 4; o >= 1; o >>= 1) sm += __shfl_xor(sm, o, 8);
  float pr = ex / sm;
  __shared__ float ps[8];
  if (L < 8) { probs[(size_t)n * 8 + L] = pr; ps[L] = pr; }
  __syncthreads();
  if (L == 0) {
    int i1 = 0; float v1 = ps[0];
#pragma unroll
    for (int e = 1; e < 8; ++e) if (ps[e] > v1) { v1 = ps[e]; i1 = e; }
    float v2 = -1.f; int i2 = 0;
#pragma unroll
    for (int e = 0; e < 8; ++e) if (e != i1 && ps[e] > v2) { v2 = ps[e]; i2 = e; }
    float s = v1 + v2;
    float w[8];
#pragma unroll
    for (int e = 0; e < 8; ++e) w[e] = 0.f;
    w[i1] = v1 / s; w[i2] = v2 / s;
#pragma unroll
    for (int e = 0; e < 8; ++e) wfull[(size_t)n * 8 + e] = w[e];
  }
}

// ---------------- weighted expert combine -> pk bf16 (K=64 for c2s) ----------------
__global__ void combine_kernel(const float* __restrict__ eo, const float* __restrict__ wfull,
                               ushort* __restrict__ exopk, int M) {
  int t = blockIdx.x * 256 + threadIdx.x;
  int n = t >> 6, m = t & 63;
  float acc = 0.f;
#pragma unroll
  for (int e = 0; e < 8; ++e)
    acc = fmaf(wfull[(size_t)n * 8 + e], eo[((size_t)e * M + n) * 64 + m], acc);
  exopk[((size_t)(m >> 3) * M + n) * 8 + (m & 7)] = f2bf(acc);
}

extern "C" void kernel_launch(void* const* d_in, const int* in_sizes, int n_in,
                              void* d_out, int out_size, void* d_ws, size_t ws_size,
                              hipStream_t stream) {
  const int*   ids   = (const int*)  d_in[0];
  const float* emb   = (const float*)d_in[1];
  const float* enc_W = (const float*)d_in[2];
  const float* enc_b = (const float*)d_in[3];
  const float* s2c_W = (const float*)d_in[4];
  const float* s2c_b = (const float*)d_in[5];
  const float* rW1   = (const float*)d_in[6];
  const float* rb1   = (const float*)d_in[7];
  const float* rW2   = (const float*)d_in[8];
  const float* rb2   = (const float*)d_in[9];
  const float* eW1   = (const float*)d_in[10];
  const float* eb1   = (const float*)d_in[11];
  const float* eW2   = (const float*)d_in[12];
  const float* eb2   = (const float*)d_in[13];
  const float* c2s_W = (const float*)d_in[14];
  const float* c2s_b = (const float*)d_in[15];
  const float* dec_W = (const float*)d_in[16];
  const float* dec_b = (const float*)d_in[17];
  const float* out_W = (const float*)d_in[18];
  const float* out_b = (const float*)d_in[19];
  (void)in_sizes; (void)n_in; (void)out_size; (void)ws_size;

  const int M = 4096, D = 1024, H = 1024, Mm = 64, E = 8, V = 32000, HE = 512;

  char* p = (char*)d_ws;
  auto alloc = [&](size_t bytes) { void* r = (void*)p; p += (bytes + 255) & ~(size_t)255; return r; };
  ushort* xpk    = (ushort*)alloc((size_t)M * D * 2);
  ushort* encWpk = (ushort*)alloc((size_t)D * H * 2);
  float*  spikes = (float*) alloc((size_t)M * H * 4);
  float*  cont   = (float*) alloc((size_t)M * Mm * 4);
  ushort* contpk = (ushort*)alloc((size_t)M * Mm * 2);
  float*  wfull  = (float*) alloc((size_t)M * E * 4);
  ushort* eW1pk  = (ushort*)alloc((size_t)E * Mm * HE * 2);
  ushort* eW2pk  = (ushort*)alloc((size_t)E * HE * Mm * 2);
  ushort* h1pk   = (ushort*)alloc((size_t)E * M * HE * 2);
  float*  eo     = (float*) alloc((size_t)E * M * Mm * 4);
  ushort* exopk  = (ushort*)alloc((size_t)M * Mm * 2);
  ushort* c2sWpk = (ushort*)alloc((size_t)Mm * H * 2);
  ushort* smoepk = (ushort*)alloc((size_t)M * H * 2);
  ushort* decWpk = (ushort*)alloc((size_t)H * D * 2);
  ushort* decpk  = (ushort*)alloc((size_t)M * D * 2);
  ushort* outWpk = (ushort*)alloc((size_t)D * V * 2);

  float* logits = (float*)d_out;
  float* probs  = logits + (size_t)M * V;

  // one-time: allow 128KB dynamic LDS for the pipelined vocab GEMM
  static bool attr_done = false;
  if (!attr_done) {
    (void)hipFuncSetAttribute(reinterpret_cast<const void*>(&gemm_out_pipe<4096, 32000, 1024>),
                              hipFuncAttributeMaxDynamicSharedMemorySize, 131072);
    attr_done = true;
  }

  // weight packs (fp32 -> bf16 k-packed)
  pack_w_kernel<<<dim3(((D / 8) * H + 255) / 256, 1), 256, 0, stream>>>(enc_W, encWpk, D, H);
  pack_w_kernel<<<dim3(((Mm / 8) * HE + 255) / 256, E), 256, 0, stream>>>(eW1, eW1pk, Mm, HE);
  pack_w_kernel<<<dim3(((HE / 8) * Mm + 255) / 256, E), 256, 0, stream>>>(eW2, eW2pk, HE, Mm);
  pack_w_kernel<<<dim3(((Mm / 8) * H + 255) / 256, 1), 256, 0, stream>>>(c2s_W, c2sWpk, Mm, H);
  pack_w_kernel<<<dim3(((H / 8) * D + 255) / 256, 1), 256, 0, stream>>>(dec_W, decWpk, H, D);
  pack_w_kernel<<<dim3(((D / 8) * V + 255) / 256, 1), 256, 0, stream>>>(out_W, outWpk, D, V);

  // 1) embed gather -> pk
  embed_pk_kernel<<<dim3(M / 256, D / 8), 256, 0, stream>>>(ids, emb, xpk, M);
  // 2) enc: sigmoid(x @ enc_W + b) -> fp32 (router path needs precision)
  gemm_pk<2, 2, 4, 4, 1, 0><<<dim3(M / 128, H / 128, 1), 256, 0, stream>>>(
      xpk, encWpk, enc_b, spikes, M, H, D, 0, 0, 0, 0);
  // 3) s2c fp32
  s2c_kernel<<<dim3(M / 4), 256, 0, stream>>>(spikes, s2c_W, s2c_b, cont, contpk, M);
  // 4) router fp32
  router_kernel<<<dim3(M), 64, 0, stream>>>(cont, rW1, rb1, rW2, rb2, probs, wfull);
  // 5) experts: h1 = relu(cont @ eW1 + eb1)  [batched over E]
  gemm_pk<2, 2, 4, 4, 2, 1><<<dim3(M / 128, HE / 128, E), 256, 0, stream>>>(
      contpk, eW1pk, eb1, h1pk, M, HE, Mm, 0, (long)Mm * HE, HE, (long)M * HE);
  //    eo = h1 @ eW2 + eb2   (N=64 tile variant)
  gemm_pk<4, 1, 2, 4, 0, 0><<<dim3(M / 128, 1, E), 256, 0, stream>>>(
      h1pk, eW2pk, eb2, eo, M, Mm, HE, (long)M * HE, (long)HE * Mm, Mm, (long)M * Mm);
  // 6) weighted combine (top-2 weights, zeros elsewhere)
  combine_kernel<<<dim3(M * Mm / 256), 256, 0, stream>>>(eo, wfull, exopk, M);
  // 7) c2s: sigmoid(expert_out @ c2s_W + b) -> pk
  gemm_pk<2, 2, 4, 4, 1, 1><<<dim3(M / 128, H / 128, 1), 256, 0, stream>>>(
      exopk, c2sWpk, c2s_b, smoepk, M, H, Mm, 0, 0, 0, 0);
  // 8) dec: sigmoid(spikes @ dec_W + b) -> pk
  gemm_pk<2, 2, 4, 4, 1, 1><<<dim3(M / 128, D / 128, 1), 256, 0, stream>>>(
      smoepk, decWpk, dec_b, decpk, M, D, H, 0, 0, 0, 0);
  // 9) out: logits = decoded @ out_W + b  (268 GFLOP) — A-read-ahead pipelined kernel
  gemm_out_pipe<4096, 32000, 1024><<<dim3((M / 256) * (V / 256)), 512, 131072, stream>>>(
      decpk, outWpk, out_b, logits);
}